// Round 11
// baseline (242.387 us; speedup 1.0000x reference)
//
#include <hip/hip_runtime.h>
#include <hip/hip_bf16.h>
#include <stdint.h>

typedef __bf16 bf16_t;
typedef bf16_t bf16x8 __attribute__((ext_vector_type(8)));
typedef bf16_t bf16x2 __attribute__((ext_vector_type(2)));
typedef float  f32x4  __attribute__((ext_vector_type(4)));
typedef float  f32x2  __attribute__((ext_vector_type(2)));

#define N_FEAT 128
#define NBMAX  196      // max node-buckets of 512 (supports N <= 100352)
#define BINB   512      // blocks in bin/scatter phase (perm code assumes 512)

// ---- legacy width-detect kernel (fallback plans) ----
__global__ void detect_k(const int* __restrict__ edges, int* __restrict__ flag) {
    int v = edges[2 * threadIdx.x + 1];          // 64 high words (if int64)
    unsigned long long m = __ballot(v != 0);
    if (threadIdx.x == 0) *flag = (m == 0ull) ? 1 : 0;
}
__device__ inline int eread(const int* __restrict__ edges, int f, long i) {
    return f ? edges[2 * i] : edges[i];
}

// per-block inline width detect (wave 0 checks 64 high words) [round-6 proven]
__device__ inline int detect_inline(const int* __restrict__ edges, int* sh) {
    if (threadIdx.x < 64) {
        int v = edges[2 * threadIdx.x + 1];
        unsigned long long m = __ballot(v != 0);
        if (threadIdx.x == 0) sh[0] = (m == 0ull) ? 1 : 0;
    }
    __syncthreads();
    return sh[0];
}

__device__ inline bf16x8 cvt8(const float* __restrict__ p) {
    f32x4 lo = *(const f32x4*)p;
    f32x4 hi = *(const f32x4*)(p + 4);
    bf16x8 r;
    r[0] = (bf16_t)lo[0]; r[1] = (bf16_t)lo[1]; r[2] = (bf16_t)lo[2]; r[3] = (bf16_t)lo[3];
    r[4] = (bf16_t)hi[0]; r[5] = (bf16_t)hi[1]; r[6] = (bf16_t)hi[2]; r[7] = (bf16_t)hi[3];
    return r;
}

// block-wide inclusive scan (blockDim multiple of 64), 1 internal barrier
__device__ inline int block_scan_incl(int v, int* wsum /*shared, >=8 ints*/) {
    const int t = threadIdx.x, lane = t & 63, wid = t >> 6;
    int x = v;
#pragma unroll
    for (int off = 1; off < 64; off <<= 1) {
        int y = __shfl_up(x, off);
        if (lane >= off) x += y;
    }
    if (lane == 63) wsum[wid] = x;
    __syncthreads();
    int add = 0;
    for (int w = 0; w < wid; ++w) add += wsum[w];
    return x + add;
}

// one 16-row GEMM tile per wave, dinv-prescaled epilogue:
// Xhat'[r] = dinv[r] * (X @ W^T)[r]  (bf16 out)
//   A: lane holds A[row=lane&15][k=(lane>>4)*8+i]
//   B: lane holds B[k][col=lane&15] == W[col][k] (K-contig)
//   D: col=lane&15, row=(lane>>4)*4+reg   [m89/m91]
__device__ inline void gemm_tile_s(long tile, const float* __restrict__ X,
                                   const bf16_t* __restrict__ Wbf,
                                   const float* __restrict__ dinv,
                                   bf16_t* __restrict__ Xhat, int lane) {
    const int m  = lane & 15;
    const int kq = lane >> 4;
    const long r0 = tile * 16;
    f32x4 acc[8];
#pragma unroll
    for (int c = 0; c < 8; ++c) acc[c] = (f32x4){0.f, 0.f, 0.f, 0.f};
    const float* xrow = X + (r0 + m) * N_FEAT + kq * 8;
#pragma unroll
    for (int kb = 0; kb < 4; ++kb) {
        bf16x8 a = cvt8(xrow + kb * 32);
#pragma unroll
        for (int c = 0; c < 8; ++c) {
            bf16x8 b = *(const bf16x8*)(Wbf + (c * 16 + m) * N_FEAT + kb * 32 + kq * 8);
            acc[c] = __builtin_amdgcn_mfma_f32_16x16x32_bf16(a, b, acc[c], 0, 0, 0);
        }
    }
    float dr[4];
#pragma unroll
    for (int i = 0; i < 4; ++i) dr[i] = dinv[r0 + kq * 4 + i];
#pragma unroll
    for (int c = 0; c < 8; ++c)
#pragma unroll
        for (int i = 0; i < 4; ++i) {
            long r = r0 + kq * 4 + i;
            Xhat[r * N_FEAT + c * 16 + m] = (bf16_t)(dr[i] * acc[c][i]);
        }
}

// ======================= Plan S: bucket-sort pipeline =======================
// Buckets of 512 nodes: rb=r>>9 (fam 0), cb=c>>9 (fam 1). LDS histograms;
// global writes are sequential per-bucket runs.
// hist/baseTab layout: [bucket j][bin-block blk].

// K1: blocks [0,BINB) = bin histogram; [BINB,BINB+64) = W->bf16 convert;
// block BINB+64 zeroes the Xhat pad row (disjoint roles, no cross-block deps).
__global__ __launch_bounds__(256) void bin_k(const int* __restrict__ edges,
                                             int E, int N, int NB,
                                             int* __restrict__ hist,
                                             const float* __restrict__ W,
                                             bf16_t* __restrict__ Wbf,
                                             bf16_t* __restrict__ xpad) {
    const int bid = blockIdx.x;
    if (bid >= BINB) {                               // aux roles
        const int b2 = bid - BINB;
        if (b2 < 64) {
            int i = b2 * 256 + threadIdx.x;          // 64 blocks x 256 = 16384
            Wbf[i] = (bf16_t)W[i];
        } else if (threadIdx.x < N_FEAT) {
            xpad[threadIdx.x] = (bf16_t)0.0f;        // gather tail lands here
        }
        return;
    }
    __shared__ int h[2 * NBMAX];
    __shared__ int shf[1];
    const int f = detect_inline(edges, shf);
    const int nb2 = 2 * NB;
    for (int j = threadIdx.x; j < nb2; j += 256) h[j] = 0;
    __syncthreads();
    const int chunk = (E + BINB - 1) / BINB;
    const int e0 = bid * chunk, e1 = min(E, e0 + chunk);
    if (f) {
        const int2* e2 = (const int2*)edges;
        for (int e = e0 + (int)threadIdx.x; e < e1; e += 256) {
            int r = e2[e].x, c = e2[(long)E + e].x;
            if ((unsigned)r < (unsigned)N && (unsigned)c < (unsigned)N) {
                atomicAdd(&h[r >> 9], 1);
                atomicAdd(&h[NB + (c >> 9)], 1);
            }
        }
    } else {
        for (int e = e0 + (int)threadIdx.x; e < e1; e += 256) {
            int r = edges[e], c = edges[(long)E + e];
            if ((unsigned)r < (unsigned)N && (unsigned)c < (unsigned)N) {
                atomicAdd(&h[r >> 9], 1);
                atomicAdd(&h[NB + (c >> 9)], 1);
            }
        }
    }
    __syncthreads();
    for (int j = threadIdx.x; j < nb2; j += 256) hist[(long)j * BINB + bid] = h[j];
}

// per-bucket exclusive scan over BINB block counts.
// XCD-GROUPED RANK ORDER: rank t -> block b=(t&63)*8+(t>>6), so consecutive
// sub-segments within a bucket belong to blocks with the same blk%8 (same XCD
// under round-robin dispatch) -> no cross-XCD false sharing on the 128B lines
// that bscatter writes. Any fixed permutation is correct (order-free segments).
__global__ __launch_bounds__(BINB) void scan_k(const int* __restrict__ hist, int NB,
                                               int* __restrict__ baseTab,
                                               int* __restrict__ totals) {
    __shared__ int wsum[BINB / 64];
    const int j = blockIdx.x;          // combined bucket id in [0, 2*NB)
    const int t = threadIdx.x;         // rank
    const int b = ((t & 63) << 3) | (t >> 6);       // rank -> bin-block id
    int v = hist[(long)j * BINB + b];
    int incl = block_scan_incl(v, wsum);
    baseTab[(long)j * BINB + b] = incl - v;
    if (t == BINB - 1) totals[j] = incl;
}

// parallel scan over the 2*NB bucket totals -> famBase; start[N] sentinel
__global__ __launch_bounds__(512) void bucketbase_k(const int* __restrict__ totals,
                                                    int NB, int N,
                                                    int* __restrict__ famBase,
                                                    int* __restrict__ start) {
    __shared__ int wsum[8];
    __shared__ int sh_tot0;
    const int t = threadIdx.x;
    const int nb2 = 2 * NB;
    int v = (t < nb2) ? totals[t] : 0;
    int incl = block_scan_incl(v, wsum);
    int excl = incl - v;
    if (t == NB) sh_tot0 = excl;       // sum of family 0
    __syncthreads();
    if (t < NB) famBase[t] = excl;
    if (t == NB) { famBase[NB] = excl; start[N] = excl; }
    if (t >= NB && t < nb2) famBase[NB + 1 + (t - NB)] = excl - sh_tot0;
    if (t == nb2 - 1) famBase[NB + 1 + NB] = incl - sh_tot0;
}

// scatter edges into bucket regions; cursors in LDS.
// rowbuf: (lrow<<17)|col, bucketed by row. colbuf: lcol, bucketed by col.
__global__ __launch_bounds__(256) void bscatter_k(const int* __restrict__ edges,
                                                  int E, int N, int NB,
                                                  const int* __restrict__ baseTab,
                                                  const int* __restrict__ famBase,
                                                  unsigned* __restrict__ rowbuf,
                                                  int* __restrict__ colbuf) {
    __shared__ int cur[2 * NBMAX];
    __shared__ int shf[1];
    const int f = detect_inline(edges, shf);
    const int blk = blockIdx.x;
    const int nb2 = 2 * NB;
    for (int j = threadIdx.x; j < nb2; j += 256) {
        int fb = (j < NB) ? famBase[j] : famBase[NB + 1 + (j - NB)];
        cur[j] = fb + baseTab[(long)j * BINB + blk];
    }
    __syncthreads();
    const int chunk = (E + BINB - 1) / BINB;
    const int e0 = blk * chunk, e1 = min(E, e0 + chunk);
    if (f) {
        const int2* e2 = (const int2*)edges;
        for (int e = e0 + (int)threadIdx.x; e < e1; e += 256) {
            int r = e2[e].x, c = e2[(long)E + e].x;
            if ((unsigned)r < (unsigned)N && (unsigned)c < (unsigned)N) {
                int pr = atomicAdd(&cur[r >> 9], 1);
                rowbuf[pr] = ((unsigned)(r & 511) << 17) | (unsigned)c;
                int pc = atomicAdd(&cur[NB + (c >> 9)], 1);
                colbuf[pc] = c & 511;
            }
        }
    } else {
        for (int e = e0 + (int)threadIdx.x; e < e1; e += 256) {
            int r = edges[e], c = edges[(long)E + e];
            if ((unsigned)r < (unsigned)N && (unsigned)c < (unsigned)N) {
                int pr = atomicAdd(&cur[r >> 9], 1);
                rowbuf[pr] = ((unsigned)(r & 511) << 17) | (unsigned)c;
                int pc = atomicAdd(&cur[NB + (c >> 9)], 1);
                colbuf[pc] = c & 511;
            }
        }
    }
}

// K5: col-degree -> dinv (one block per col bucket)
__global__ __launch_bounds__(512) void coldeg_k(const int* __restrict__ colbuf,
                                                const int* __restrict__ famBase,
                                                int NB, int N,
                                                float* __restrict__ dinv) {
    __shared__ int cnt[512];
    const int t = threadIdx.x;
    const int b = blockIdx.x;
    cnt[t] = 0;
    __syncthreads();
    const int e0 = famBase[NB + 1 + b], e1 = famBase[NB + 1 + b + 1];
    for (int e = e0 + t; e < e1; e += 512)
        atomicAdd(&cnt[colbuf[e]], 1);
    __syncthreads();
    int n = (b << 9) + t;
    if (n < N) dinv[n] = rsqrtf((float)(cnt[t] + 1));
}

// K6: blocks [0,NB) row-CSR; [NB,..) GEMM tiles (8/block) — dinv ready (K5).
__global__ __launch_bounds__(512) void rowgemm_k(const unsigned* __restrict__ rowbuf,
                                                 const int* __restrict__ famBase,
                                                 int NB, int N, int ntiles,
                                                 int* __restrict__ start,
                                                 int* __restrict__ ecol,
                                                 const float* __restrict__ X,
                                                 const bf16_t* __restrict__ Wbf,
                                                 const float* __restrict__ dinv,
                                                 bf16_t* __restrict__ Xhat) {
    const int t = threadIdx.x;
    const int bid = blockIdx.x;
    if (bid >= NB) {                                 // GEMM role: 8 tiles/block
        const long tile = (long)(bid - NB) * 8 + (t >> 6);
        if (tile < ntiles) gemm_tile_s(tile, X, Wbf, dinv, Xhat, t & 63);
        return;
    }
    __shared__ int cnt[512];
    __shared__ int wsum[8];
    const int b = bid;                               // row bucket
    cnt[t] = 0;
    __syncthreads();
    const int e0 = famBase[b], e1 = famBase[b + 1];
    for (int e = e0 + t; e < e1; e += 512)
        atomicAdd(&cnt[rowbuf[e] >> 17], 1);
    __syncthreads();
    int v = cnt[t];
    int incl = block_scan_incl(v, wsum);
    int excl = incl - v;
    const int n = (b << 9) + t;
    if (n < N) start[n] = e0 + excl;
    cnt[t] = e0 + excl;                              // reuse as cursor
    __syncthreads();
    for (int e = e0 + t; e < e1; e += 512) {
        unsigned w = rowbuf[e];
        int pos = atomicAdd(&cnt[w >> 17], 1);
        ecol[pos] = (int)(w & 0x1FFFFu);
    }
}

// one wave per node; lane j owns features 2j,2j+1. 8-wide padded unroll
// (round-9 proven body: 63.3 µs, VGPR 16). Xhat pre-scaled; tail -> pad row N.
__global__ __launch_bounds__(64) void gather5_k(const int* __restrict__ ecol,
                                                const int* __restrict__ start,
                                                const float* __restrict__ dinv,
                                                const bf16_t* __restrict__ Xhat,
                                                int N,
                                                float* __restrict__ out) {
    const int n = blockIdx.x;
    const int j = threadIdx.x;
    const int s = start[n], e = start[n + 1];

    bf16x2 xs = *(const bf16x2*)(Xhat + (long)n * N_FEAT + 2 * j);
    float a0 = (float)xs[0];           // self-loop term (pre-scaled)
    float a1 = (float)xs[1];

    for (int p = s; p < e; p += 8) {
        int cq[8];
#pragma unroll
        for (int q = 0; q < 8; ++q) {
            int tt = p + q;
            int idx = (tt < e) ? tt : s;             // safe clamp (e > s here)
            int cc = ecol[idx];
            cq[q] = (tt < e) ? cc : N;               // tail -> zero pad row
        }
#pragma unroll
        for (int q = 0; q < 8; ++q) {
            bf16x2 xv = *(const bf16x2*)(Xhat + (long)cq[q] * N_FEAT + 2 * j);
            a0 += (float)xv[0];
            a1 += (float)xv[1];
        }
    }
    const float dn = dinv[n];
    f32x2 o; o[0] = dn * a0; o[1] = dn * a1;
    *(f32x2*)(out + (long)n * N_FEAT + 2 * j) = o;
}

// ============ Plan A (fallback): order-free CSR + gather ============

__global__ __launch_bounds__(64) void gemm_xwt(const float* __restrict__ X,
                                               const float* __restrict__ W,
                                               bf16_t* __restrict__ Xhat) {
    const int lane = threadIdx.x;
    const int m  = lane & 15;
    const int kq = lane >> 4;
    const long r0 = (long)blockIdx.x * 16;
    f32x4 acc[8];
#pragma unroll
    for (int c = 0; c < 8; ++c) acc[c] = (f32x4){0.f, 0.f, 0.f, 0.f};
    const float* xrow = X + (r0 + m) * N_FEAT + kq * 8;
#pragma unroll
    for (int kb = 0; kb < 4; ++kb) {
        bf16x8 a = cvt8(xrow + kb * 32);
#pragma unroll
        for (int c = 0; c < 8; ++c) {
            bf16x8 b = cvt8(W + (c * 16 + m) * N_FEAT + kb * 32 + kq * 8);
            acc[c] = __builtin_amdgcn_mfma_f32_16x16x32_bf16(a, b, acc[c], 0, 0, 0);
        }
    }
#pragma unroll
    for (int c = 0; c < 8; ++c)
#pragma unroll
        for (int i = 0; i < 4; ++i) {
            long r = r0 + kq * 4 + i;
            Xhat[r * N_FEAT + c * 16 + m] = (bf16_t)acc[c][i];
        }
}

__global__ void degree_k(const int* __restrict__ edges, const int* __restrict__ flag,
                         int E, int N,
                         int* __restrict__ cnt_row, int* __restrict__ cnt_col) {
    int e = blockIdx.x * blockDim.x + threadIdx.x;
    int f = *flag;
    if (e < E) {
        int r = eread(edges, f, e);
        int c = eread(edges, f, (long)E + e);
        if ((unsigned)r < (unsigned)N) atomicAdd(&cnt_row[r], 1);
        if ((unsigned)c < (unsigned)N) atomicAdd(&cnt_col[c], 1);
    }
}

__global__ void degree_col_k(const int* __restrict__ edges, const int* __restrict__ flag,
                             int E, int N, int* __restrict__ cnt_col) {
    int e = blockIdx.x * blockDim.x + threadIdx.x;
    int f = *flag;
    if (e < E) {
        int c = eread(edges, f, (long)E + e);
        if ((unsigned)c < (unsigned)N) atomicAdd(&cnt_col[c], 1);
    }
}

__global__ void alloc_k(const int* __restrict__ cnt_row, int N,
                        int* __restrict__ cur, int* __restrict__ total,
                        int* cnt_col_in, float* dinv_out) {
    int n = blockIdx.x * blockDim.x + threadIdx.x;
    if (n < N) {
        cur[n] = atomicAdd(total, cnt_row[n]);
        int dc = cnt_col_in[n];
        dinv_out[n] = rsqrtf((float)(dc + 1));
    }
}

__global__ void scatter_k(const int* __restrict__ edges, const int* __restrict__ flag,
                          int E, int N, int* __restrict__ cur, int* __restrict__ ecol) {
    int e = blockIdx.x * blockDim.x + threadIdx.x;
    int f = *flag;
    if (e < E) {
        int r = eread(edges, f, e);
        if ((unsigned)r < (unsigned)N) {
            int p = atomicAdd(&cur[r], 1);
            if ((unsigned)p < (unsigned)E)
                ecol[p] = eread(edges, f, (long)E + e);
        }
    }
}

__global__ __launch_bounds__(64) void gather_k(const int* __restrict__ ecol,
                                               const int* __restrict__ cur,
                                               const int* __restrict__ cnt_row,
                                               const float* __restrict__ dinv,
                                               const bf16_t* __restrict__ Xhat,
                                               int N,
                                               float* __restrict__ out) {
    const int n = blockIdx.x;
    const int j = threadIdx.x;
    const int c = cnt_row[n];
    const int s = cur[n] - c;
    const float dn = dinv[n];
    bf16x2 xs = *(const bf16x2*)(Xhat + (long)n * N_FEAT + 2 * j);
    float a0 = dn * (float)xs[0];
    float a1 = dn * (float)xs[1];
    for (int e = 0; e < c; ++e) {
        int cc = ecol[s + e];
        if ((unsigned)cc >= (unsigned)N) continue;
        float dc = dinv[cc];
        bf16x2 xv = *(const bf16x2*)(Xhat + (long)cc * N_FEAT + 2 * j);
        a0 += dc * (float)xv[0];
        a1 += dc * (float)xv[1];
    }
    f32x2 o; o[0] = dn * a0; o[1] = dn * a1;
    *(f32x2*)(out + (long)n * N_FEAT + 2 * j) = o;
}

// ============ Plan B (small ws): fp32 atomicAdd into d_out ============

__global__ __launch_bounds__(128) void self_k(const int* __restrict__ cnt_col,
                                              const bf16_t* __restrict__ Xhat,
                                              float* __restrict__ out) {
    const int n = blockIdx.x;
    const int j = threadIdx.x;
    const float dn2 = 1.0f / (float)(cnt_col[n] + 1);
    out[(long)n * N_FEAT + j] = dn2 * (float)Xhat[(long)n * N_FEAT + j];
}

__global__ __launch_bounds__(128) void edge_add_k(const int* __restrict__ edges,
                                                  const int* __restrict__ flag,
                                                  int E, int N,
                                                  const int* __restrict__ cnt_col,
                                                  const bf16_t* __restrict__ Xhat,
                                                  float* __restrict__ out) {
    const int e = blockIdx.x;
    const int j = threadIdx.x;
    int f = *flag;
    const int r = eread(edges, f, e);
    const int c = eread(edges, f, (long)E + e);
    if ((unsigned)r >= (unsigned)N || (unsigned)c >= (unsigned)N) return;
    const float val = rsqrtf((float)(cnt_col[r] + 1)) * rsqrtf((float)(cnt_col[c] + 1));
    atomicAdd(&out[(long)r * N_FEAT + j], val * (float)Xhat[(long)c * N_FEAT + j]);
}

extern "C" void kernel_launch(void* const* d_in, const int* in_sizes, int n_in,
                              void* d_out, int out_size, void* d_ws, size_t ws_size,
                              hipStream_t stream) {
    const float* X = (const float*)d_in[0];
    const float* W = (const float*)d_in[1];
    const int* edges = (const int*)d_in[2];
    const int E = in_sizes[2] / 2;          // 1,600,000
    const int N = in_sizes[0] / N_FEAT;     // 100,000
    const int NB = (N + 511) >> 9;          // buckets of 512 nodes (196)

    char* ws = (char*)d_ws;
    const size_t xhat_b = (size_t)(N + 1) * N_FEAT * sizeof(bf16_t);  // +1 pad row
    const size_t n4     = (size_t)N * 4;
    auto al = [](size_t x) { return (x + 255) & ~(size_t)255; };

    // ---- Plan S layout (256-aligned; Xhat rows = exactly 4 cache lines) ----
    size_t off = 0;
    int*      flag   = (int*)(ws + off);        off = 256;
    bf16_t*   Wbf    = (bf16_t*)(ws + off);     off = al(off + 128 * 128 * 2);
    bf16_t*   Xhat   = (bf16_t*)(ws + off);     off = al(off + xhat_b);
    float*    dinv   = (float*)(ws + off);      off = al(off + n4);
    int*      startA = (int*)(ws + off);        off = al(off + n4 + 4);
    unsigned* rowbuf = (unsigned*)(ws + off);   off = al(off + (size_t)E * 4);
    int*      colbuf = (int*)(ws + off);        off = al(off + (size_t)E * 4);
    int*      ecol   = (int*)(ws + off);        off = al(off + (size_t)E * 4);
    int*      hist   = (int*)(ws + off);        off = al(off + (size_t)BINB * 2 * NB * 4);
    int*      baseTab= (int*)(ws + off);        off = al(off + (size_t)BINB * 2 * NB * 4);
    int*      totals = (int*)(ws + off);        off = al(off + (size_t)(2 * NB) * 4);
    int*      famBase= (int*)(ws + off);        off = al(off + (size_t)(2 * NB + 2) * 4);
    const size_t need_S = off;

    int* cnt_col = (int*)(ws + 16 + xhat_b);
    const size_t need_A = 16 + xhat_b + n4 * 3 + 16 + (size_t)E * 4;
    const size_t need_B = 16 + xhat_b + n4;

    if (ws_size >= need_S && NB <= NBMAX && N <= 100352 && (N & 15) == 0 && E >= BINB) {
        const int ntiles = N / 16;                       // 6250
        const int GEMMB  = (ntiles + 7) / 8;             // 782
        bin_k<<<BINB + 65, 256, 0, stream>>>(edges, E, N, NB, hist,
                                             W, Wbf, Xhat + (size_t)N * N_FEAT);
        scan_k<<<2 * NB, BINB, 0, stream>>>(hist, NB, baseTab, totals);
        bucketbase_k<<<1, 512, 0, stream>>>(totals, NB, N, famBase, startA);
        bscatter_k<<<BINB, 256, 0, stream>>>(edges, E, N, NB, baseTab, famBase,
                                             rowbuf, colbuf);
        coldeg_k<<<NB, 512, 0, stream>>>(colbuf, famBase, NB, N, dinv);
        rowgemm_k<<<NB + GEMMB, 512, 0, stream>>>(rowbuf, famBase, NB, N, ntiles,
                                                  startA, ecol, X, Wbf, dinv, Xhat);
        gather5_k<<<N, 64, 0, stream>>>(ecol, startA, dinv, Xhat, N, (float*)d_out);
    } else if (ws_size >= need_A) {
        bf16_t* XhatA  = (bf16_t*)(ws + 16);
        int*   cnt_row = (int*)(ws + 16 + xhat_b + n4);
        int*   cur     = (int*)(ws + 16 + xhat_b + n4 * 2);
        int*   total   = (int*)(ws + 16 + xhat_b + n4 * 3);
        int*   ecolA   = (int*)(ws + 16 + xhat_b + n4 * 3 + 16);
        float* dinvA   = (float*)cnt_col;

        hipMemsetAsync(cnt_col, 0, n4 * 2, stream);
        hipMemsetAsync(total, 0, 16, stream);
        detect_k<<<1, 64, 0, stream>>>(edges, flag);
        gemm_xwt<<<N / 16, 64, 0, stream>>>(X, W, XhatA);
        degree_k<<<(E + 255) / 256, 256, 0, stream>>>(edges, flag, E, N, cnt_row, cnt_col);
        alloc_k<<<(N + 255) / 256, 256, 0, stream>>>(cnt_row, N, cur, total, cnt_col, dinvA);
        scatter_k<<<(E + 255) / 256, 256, 0, stream>>>(edges, flag, E, N, cur, ecolA);
        gather_k<<<N, 64, 0, stream>>>(ecolA, cur, cnt_row, dinvA, XhatA, N, (float*)d_out);
    } else if (ws_size >= need_B) {
        bf16_t* XhatB = (bf16_t*)(ws + 16);
        hipMemsetAsync(cnt_col, 0, n4, stream);
        detect_k<<<1, 64, 0, stream>>>(edges, flag);
        gemm_xwt<<<N / 16, 64, 0, stream>>>(X, W, XhatB);
        degree_col_k<<<(E + 255) / 256, 256, 0, stream>>>(edges, flag, E, N, cnt_col);
        self_k<<<N, 128, 0, stream>>>(cnt_col, XhatB, (float*)d_out);
        edge_add_k<<<E, 128, 0, stream>>>(edges, flag, E, N, cnt_col, XhatB, (float*)d_out);
    }
}

// Round 12
// 237.637 us; speedup vs baseline: 1.0200x; 1.0200x over previous
//
#include <hip/hip_runtime.h>
#include <hip/hip_bf16.h>
#include <stdint.h>

typedef __bf16 bf16_t;
typedef bf16_t bf16x8 __attribute__((ext_vector_type(8)));
typedef bf16_t bf16x2 __attribute__((ext_vector_type(2)));
typedef float  f32x4  __attribute__((ext_vector_type(4)));
typedef float  f32x2  __attribute__((ext_vector_type(2)));

#define N_FEAT 128
#define NBMAX  196      // max node-buckets of 512 (supports N <= 100352)
#define BINB   512      // blocks in bin/scatter phase (perm code assumes 512)

// ---- legacy width-detect kernel (fallback plans) ----
__global__ void detect_k(const int* __restrict__ edges, int* __restrict__ flag) {
    int v = edges[2 * threadIdx.x + 1];          // 64 high words (if int64)
    unsigned long long m = __ballot(v != 0);
    if (threadIdx.x == 0) *flag = (m == 0ull) ? 1 : 0;
}
__device__ inline int eread(const int* __restrict__ edges, int f, long i) {
    return f ? edges[2 * i] : edges[i];
}

// per-block inline width detect (wave 0 checks 64 high words) [round-6 proven]
__device__ inline int detect_inline(const int* __restrict__ edges, int* sh) {
    if (threadIdx.x < 64) {
        int v = edges[2 * threadIdx.x + 1];
        unsigned long long m = __ballot(v != 0);
        if (threadIdx.x == 0) sh[0] = (m == 0ull) ? 1 : 0;
    }
    __syncthreads();
    return sh[0];
}

__device__ inline bf16x8 cvt8(const float* __restrict__ p) {
    f32x4 lo = *(const f32x4*)p;
    f32x4 hi = *(const f32x4*)(p + 4);
    bf16x8 r;
    r[0] = (bf16_t)lo[0]; r[1] = (bf16_t)lo[1]; r[2] = (bf16_t)lo[2]; r[3] = (bf16_t)lo[3];
    r[4] = (bf16_t)hi[0]; r[5] = (bf16_t)hi[1]; r[6] = (bf16_t)hi[2]; r[7] = (bf16_t)hi[3];
    return r;
}

// block-wide inclusive scan (blockDim multiple of 64), 1 internal barrier
__device__ inline int block_scan_incl(int v, int* wsum /*shared, >=nwaves ints*/) {
    const int t = threadIdx.x, lane = t & 63, wid = t >> 6;
    int x = v;
#pragma unroll
    for (int off = 1; off < 64; off <<= 1) {
        int y = __shfl_up(x, off);
        if (lane >= off) x += y;
    }
    if (lane == 63) wsum[wid] = x;
    __syncthreads();
    int add = 0;
    for (int w = 0; w < wid; ++w) add += wsum[w];
    return x + add;
}

// one 16-row GEMM tile per wave, dinv-prescaled epilogue:
// Xhat'[r] = dinv[r] * (X @ W^T)[r]  (bf16 out)
//   A: lane holds A[row=lane&15][k=(lane>>4)*8+i]
//   B: lane holds B[k][col=lane&15] == W[col][k] (K-contig)
//   D: col=lane&15, row=(lane>>4)*4+reg   [m89/m91]
__device__ inline void gemm_tile_s(long tile, const float* __restrict__ X,
                                   const bf16_t* __restrict__ Wbf,
                                   const float* __restrict__ dinv,
                                   bf16_t* __restrict__ Xhat, int lane) {
    const int m  = lane & 15;
    const int kq = lane >> 4;
    const long r0 = tile * 16;
    f32x4 acc[8];
#pragma unroll
    for (int c = 0; c < 8; ++c) acc[c] = (f32x4){0.f, 0.f, 0.f, 0.f};
    const float* xrow = X + (r0 + m) * N_FEAT + kq * 8;
#pragma unroll
    for (int kb = 0; kb < 4; ++kb) {
        bf16x8 a = cvt8(xrow + kb * 32);
#pragma unroll
        for (int c = 0; c < 8; ++c) {
            bf16x8 b = *(const bf16x8*)(Wbf + (c * 16 + m) * N_FEAT + kb * 32 + kq * 8);
            acc[c] = __builtin_amdgcn_mfma_f32_16x16x32_bf16(a, b, acc[c], 0, 0, 0);
        }
    }
    float dr[4];
#pragma unroll
    for (int i = 0; i < 4; ++i) dr[i] = dinv[r0 + kq * 4 + i];
#pragma unroll
    for (int c = 0; c < 8; ++c)
#pragma unroll
        for (int i = 0; i < 4; ++i) {
            long r = r0 + kq * 4 + i;
            Xhat[r * N_FEAT + c * 16 + m] = (bf16_t)(dr[i] * acc[c][i]);
        }
}

// ======================= Plan S: bucket-sort pipeline =======================
// Buckets of 512 nodes: rb=r>>9 (fam 0), cb=c>>9 (fam 1). LDS histograms;
// global writes are sequential per-bucket runs.
// hist/baseTab layout: [bucket j][bin-block blk].

// K1: blocks [0,BINB) = bin histogram (1024 thr: 100% slot fill, latency
// hiding for the edge stream); [BINB,BINB+16) = W->bf16; BINB+16 = pad row.
__global__ __launch_bounds__(1024) void bin_k(const int* __restrict__ edges,
                                              int E, int N, int NB,
                                              int* __restrict__ hist,
                                              const float* __restrict__ W,
                                              bf16_t* __restrict__ Wbf,
                                              bf16_t* __restrict__ xpad) {
    const int bid = blockIdx.x;
    if (bid >= BINB) {                               // aux roles
        const int b2 = bid - BINB;
        if (b2 < 16) {
            int i = b2 * 1024 + threadIdx.x;         // 16 blocks x 1024 = 16384
            Wbf[i] = (bf16_t)W[i];
        } else if (threadIdx.x < N_FEAT) {
            xpad[threadIdx.x] = (bf16_t)0.0f;        // gather tail lands here
        }
        return;
    }
    __shared__ int h[2 * NBMAX];
    __shared__ int shf[1];
    const int f = detect_inline(edges, shf);
    const int nb2 = 2 * NB;
    for (int j = threadIdx.x; j < nb2; j += 1024) h[j] = 0;
    __syncthreads();
    const int chunk = (E + BINB - 1) / BINB;
    const int e0 = bid * chunk, e1 = min(E, e0 + chunk);
    if (f) {
        const int2* e2 = (const int2*)edges;
        for (int e = e0 + (int)threadIdx.x; e < e1; e += 1024) {
            int r = e2[e].x, c = e2[(long)E + e].x;
            if ((unsigned)r < (unsigned)N && (unsigned)c < (unsigned)N) {
                atomicAdd(&h[r >> 9], 1);
                atomicAdd(&h[NB + (c >> 9)], 1);
            }
        }
    } else {
        for (int e = e0 + (int)threadIdx.x; e < e1; e += 1024) {
            int r = edges[e], c = edges[(long)E + e];
            if ((unsigned)r < (unsigned)N && (unsigned)c < (unsigned)N) {
                atomicAdd(&h[r >> 9], 1);
                atomicAdd(&h[NB + (c >> 9)], 1);
            }
        }
    }
    __syncthreads();
    for (int j = threadIdx.x; j < nb2; j += 1024) hist[(long)j * BINB + bid] = h[j];
}

// per-bucket exclusive scan over BINB block counts.
// XCD-GROUPED RANK ORDER (round-11, neutral-proven): rank t -> block
// b=(t&63)*8+(t>>6). Any fixed permutation is correct (order-free segments).
__global__ __launch_bounds__(BINB) void scan_k(const int* __restrict__ hist, int NB,
                                               int* __restrict__ baseTab,
                                               int* __restrict__ totals) {
    __shared__ int wsum[BINB / 64];
    const int j = blockIdx.x;          // combined bucket id in [0, 2*NB)
    const int t = threadIdx.x;         // rank
    const int b = ((t & 63) << 3) | (t >> 6);       // rank -> bin-block id
    int v = hist[(long)j * BINB + b];
    int incl = block_scan_incl(v, wsum);
    baseTab[(long)j * BINB + b] = incl - v;
    if (t == BINB - 1) totals[j] = incl;
}

// parallel scan over the 2*NB bucket totals -> famBase; start[N] sentinel
__global__ __launch_bounds__(512) void bucketbase_k(const int* __restrict__ totals,
                                                    int NB, int N,
                                                    int* __restrict__ famBase,
                                                    int* __restrict__ start) {
    __shared__ int wsum[8];
    __shared__ int sh_tot0;
    const int t = threadIdx.x;
    const int nb2 = 2 * NB;
    int v = (t < nb2) ? totals[t] : 0;
    int incl = block_scan_incl(v, wsum);
    int excl = incl - v;
    if (t == NB) sh_tot0 = excl;       // sum of family 0
    __syncthreads();
    if (t < NB) famBase[t] = excl;
    if (t == NB) { famBase[NB] = excl; start[N] = excl; }
    if (t >= NB && t < nb2) famBase[NB + 1 + (t - NB)] = excl - sh_tot0;
    if (t == nb2 - 1) famBase[NB + 1 + NB] = incl - sh_tot0;
}

// scatter edges into bucket regions; cursors in LDS (1024 thr: full slot fill).
// rowbuf: (lrow<<17)|col, bucketed by row. colbuf: lcol, bucketed by col.
__global__ __launch_bounds__(1024) void bscatter_k(const int* __restrict__ edges,
                                                   int E, int N, int NB,
                                                   const int* __restrict__ baseTab,
                                                   const int* __restrict__ famBase,
                                                   unsigned* __restrict__ rowbuf,
                                                   int* __restrict__ colbuf) {
    __shared__ int cur[2 * NBMAX];
    __shared__ int shf[1];
    const int f = detect_inline(edges, shf);
    const int blk = blockIdx.x;
    const int nb2 = 2 * NB;
    for (int j = threadIdx.x; j < nb2; j += 1024) {
        int fb = (j < NB) ? famBase[j] : famBase[NB + 1 + (j - NB)];
        cur[j] = fb + baseTab[(long)j * BINB + blk];
    }
    __syncthreads();
    const int chunk = (E + BINB - 1) / BINB;
    const int e0 = blk * chunk, e1 = min(E, e0 + chunk);
    if (f) {
        const int2* e2 = (const int2*)edges;
        for (int e = e0 + (int)threadIdx.x; e < e1; e += 1024) {
            int r = e2[e].x, c = e2[(long)E + e].x;
            if ((unsigned)r < (unsigned)N && (unsigned)c < (unsigned)N) {
                int pr = atomicAdd(&cur[r >> 9], 1);
                rowbuf[pr] = ((unsigned)(r & 511) << 17) | (unsigned)c;
                int pc = atomicAdd(&cur[NB + (c >> 9)], 1);
                colbuf[pc] = c & 511;
            }
        }
    } else {
        for (int e = e0 + (int)threadIdx.x; e < e1; e += 1024) {
            int r = edges[e], c = edges[(long)E + e];
            if ((unsigned)r < (unsigned)N && (unsigned)c < (unsigned)N) {
                int pr = atomicAdd(&cur[r >> 9], 1);
                rowbuf[pr] = ((unsigned)(r & 511) << 17) | (unsigned)c;
                int pc = atomicAdd(&cur[NB + (c >> 9)], 1);
                colbuf[pc] = c & 511;
            }
        }
    }
}

// K5: col-degree -> dinv (one block per col bucket; 1024 thr)
__global__ __launch_bounds__(1024) void coldeg_k(const int* __restrict__ colbuf,
                                                 const int* __restrict__ famBase,
                                                 int NB, int N,
                                                 float* __restrict__ dinv) {
    __shared__ int cnt[512];
    const int t = threadIdx.x;
    const int b = blockIdx.x;
    if (t < 512) cnt[t] = 0;
    __syncthreads();
    const int e0 = famBase[NB + 1 + b], e1 = famBase[NB + 1 + b + 1];
    for (int e = e0 + t; e < e1; e += 1024)
        atomicAdd(&cnt[colbuf[e]], 1);
    __syncthreads();
    if (t < 512) {
        int n = (b << 9) + t;
        if (n < N) dinv[n] = rsqrtf((float)(cnt[t] + 1));
    }
}

// K6: blocks [0,NB) row-CSR; [NB,..) GEMM tiles (8/block) — dinv ready (K5).
__global__ __launch_bounds__(512) void rowgemm_k(const unsigned* __restrict__ rowbuf,
                                                 const int* __restrict__ famBase,
                                                 int NB, int N, int ntiles,
                                                 int* __restrict__ start,
                                                 int* __restrict__ ecol,
                                                 const float* __restrict__ X,
                                                 const bf16_t* __restrict__ Wbf,
                                                 const float* __restrict__ dinv,
                                                 bf16_t* __restrict__ Xhat) {
    const int t = threadIdx.x;
    const int bid = blockIdx.x;
    if (bid >= NB) {                                 // GEMM role: 8 tiles/block
        const long tile = (long)(bid - NB) * 8 + (t >> 6);
        if (tile < ntiles) gemm_tile_s(tile, X, Wbf, dinv, Xhat, t & 63);
        return;
    }
    __shared__ int cnt[512];
    __shared__ int wsum[8];
    const int b = bid;                               // row bucket
    cnt[t] = 0;
    __syncthreads();
    const int e0 = famBase[b], e1 = famBase[b + 1];
    for (int e = e0 + t; e < e1; e += 512)
        atomicAdd(&cnt[rowbuf[e] >> 17], 1);
    __syncthreads();
    int v = cnt[t];
    int incl = block_scan_incl(v, wsum);
    int excl = incl - v;
    const int n = (b << 9) + t;
    if (n < N) start[n] = e0 + excl;
    cnt[t] = e0 + excl;                              // reuse as cursor
    __syncthreads();
    for (int e = e0 + t; e < e1; e += 512) {
        unsigned w = rowbuf[e];
        int pos = atomicAdd(&cnt[w >> 17], 1);
        ecol[pos] = (int)(w & 0x1FFFFu);
    }
}

// one wave per node; lane j owns features 2j,2j+1. 8-wide padded unroll
// (round-9 proven body: 63.3 µs, VGPR 16). Xhat pre-scaled; tail -> pad row N.
__global__ __launch_bounds__(64) void gather5_k(const int* __restrict__ ecol,
                                                const int* __restrict__ start,
                                                const float* __restrict__ dinv,
                                                const bf16_t* __restrict__ Xhat,
                                                int N,
                                                float* __restrict__ out) {
    const int n = blockIdx.x;
    const int j = threadIdx.x;
    const int s = start[n], e = start[n + 1];

    bf16x2 xs = *(const bf16x2*)(Xhat + (long)n * N_FEAT + 2 * j);
    float a0 = (float)xs[0];           // self-loop term (pre-scaled)
    float a1 = (float)xs[1];

    for (int p = s; p < e; p += 8) {
        int cq[8];
#pragma unroll
        for (int q = 0; q < 8; ++q) {
            int tt = p + q;
            int idx = (tt < e) ? tt : s;             // safe clamp (e > s here)
            int cc = ecol[idx];
            cq[q] = (tt < e) ? cc : N;               // tail -> zero pad row
        }
#pragma unroll
        for (int q = 0; q < 8; ++q) {
            bf16x2 xv = *(const bf16x2*)(Xhat + (long)cq[q] * N_FEAT + 2 * j);
            a0 += (float)xv[0];
            a1 += (float)xv[1];
        }
    }
    const float dn = dinv[n];
    f32x2 o; o[0] = dn * a0; o[1] = dn * a1;
    *(f32x2*)(out + (long)n * N_FEAT + 2 * j) = o;
}

// ============ Plan A (fallback): order-free CSR + gather ============

__global__ __launch_bounds__(64) void gemm_xwt(const float* __restrict__ X,
                                               const float* __restrict__ W,
                                               bf16_t* __restrict__ Xhat) {
    const int lane = threadIdx.x;
    const int m  = lane & 15;
    const int kq = lane >> 4;
    const long r0 = (long)blockIdx.x * 16;
    f32x4 acc[8];
#pragma unroll
    for (int c = 0; c < 8; ++c) acc[c] = (f32x4){0.f, 0.f, 0.f, 0.f};
    const float* xrow = X + (r0 + m) * N_FEAT + kq * 8;
#pragma unroll
    for (int kb = 0; kb < 4; ++kb) {
        bf16x8 a = cvt8(xrow + kb * 32);
#pragma unroll
        for (int c = 0; c < 8; ++c) {
            bf16x8 b = cvt8(W + (c * 16 + m) * N_FEAT + kb * 32 + kq * 8);
            acc[c] = __builtin_amdgcn_mfma_f32_16x16x32_bf16(a, b, acc[c], 0, 0, 0);
        }
    }
#pragma unroll
    for (int c = 0; c < 8; ++c)
#pragma unroll
        for (int i = 0; i < 4; ++i) {
            long r = r0 + kq * 4 + i;
            Xhat[r * N_FEAT + c * 16 + m] = (bf16_t)acc[c][i];
        }
}

__global__ void degree_k(const int* __restrict__ edges, const int* __restrict__ flag,
                         int E, int N,
                         int* __restrict__ cnt_row, int* __restrict__ cnt_col) {
    int e = blockIdx.x * blockDim.x + threadIdx.x;
    int f = *flag;
    if (e < E) {
        int r = eread(edges, f, e);
        int c = eread(edges, f, (long)E + e);
        if ((unsigned)r < (unsigned)N) atomicAdd(&cnt_row[r], 1);
        if ((unsigned)c < (unsigned)N) atomicAdd(&cnt_col[c], 1);
    }
}

__global__ void degree_col_k(const int* __restrict__ edges, const int* __restrict__ flag,
                             int E, int N, int* __restrict__ cnt_col) {
    int e = blockIdx.x * blockDim.x + threadIdx.x;
    int f = *flag;
    if (e < E) {
        int c = eread(edges, f, (long)E + e);
        if ((unsigned)c < (unsigned)N) atomicAdd(&cnt_col[c], 1);
    }
}

__global__ void alloc_k(const int* __restrict__ cnt_row, int N,
                        int* __restrict__ cur, int* __restrict__ total,
                        int* cnt_col_in, float* dinv_out) {
    int n = blockIdx.x * blockDim.x + threadIdx.x;
    if (n < N) {
        cur[n] = atomicAdd(total, cnt_row[n]);
        int dc = cnt_col_in[n];
        dinv_out[n] = rsqrtf((float)(dc + 1));
    }
}

__global__ void scatter_k(const int* __restrict__ edges, const int* __restrict__ flag,
                          int E, int N, int* __restrict__ cur, int* __restrict__ ecol) {
    int e = blockIdx.x * blockDim.x + threadIdx.x;
    int f = *flag;
    if (e < E) {
        int r = eread(edges, f, e);
        if ((unsigned)r < (unsigned)N) {
            int p = atomicAdd(&cur[r], 1);
            if ((unsigned)p < (unsigned)E)
                ecol[p] = eread(edges, f, (long)E + e);
        }
    }
}

__global__ __launch_bounds__(64) void gather_k(const int* __restrict__ ecol,
                                               const int* __restrict__ cur,
                                               const int* __restrict__ cnt_row,
                                               const float* __restrict__ dinv,
                                               const bf16_t* __restrict__ Xhat,
                                               int N,
                                               float* __restrict__ out) {
    const int n = blockIdx.x;
    const int j = threadIdx.x;
    const int c = cnt_row[n];
    const int s = cur[n] - c;
    const float dn = dinv[n];
    bf16x2 xs = *(const bf16x2*)(Xhat + (long)n * N_FEAT + 2 * j);
    float a0 = dn * (float)xs[0];
    float a1 = dn * (float)xs[1];
    for (int e = 0; e < c; ++e) {
        int cc = ecol[s + e];
        if ((unsigned)cc >= (unsigned)N) continue;
        float dc = dinv[cc];
        bf16x2 xv = *(const bf16x2*)(Xhat + (long)cc * N_FEAT + 2 * j);
        a0 += dc * (float)xv[0];
        a1 += dc * (float)xv[1];
    }
    f32x2 o; o[0] = dn * a0; o[1] = dn * a1;
    *(f32x2*)(out + (long)n * N_FEAT + 2 * j) = o;
}

// ============ Plan B (small ws): fp32 atomicAdd into d_out ============

__global__ __launch_bounds__(128) void self_k(const int* __restrict__ cnt_col,
                                              const bf16_t* __restrict__ Xhat,
                                              float* __restrict__ out) {
    const int n = blockIdx.x;
    const int j = threadIdx.x;
    const float dn2 = 1.0f / (float)(cnt_col[n] + 1);
    out[(long)n * N_FEAT + j] = dn2 * (float)Xhat[(long)n * N_FEAT + j];
}

__global__ __launch_bounds__(128) void edge_add_k(const int* __restrict__ edges,
                                                  const int* __restrict__ flag,
                                                  int E, int N,
                                                  const int* __restrict__ cnt_col,
                                                  const bf16_t* __restrict__ Xhat,
                                                  float* __restrict__ out) {
    const int e = blockIdx.x;
    const int j = threadIdx.x;
    int f = *flag;
    const int r = eread(edges, f, e);
    const int c = eread(edges, f, (long)E + e);
    if ((unsigned)r >= (unsigned)N || (unsigned)c >= (unsigned)N) return;
    const float val = rsqrtf((float)(cnt_col[r] + 1)) * rsqrtf((float)(cnt_col[c] + 1));
    atomicAdd(&out[(long)r * N_FEAT + j], val * (float)Xhat[(long)c * N_FEAT + j]);
}

extern "C" void kernel_launch(void* const* d_in, const int* in_sizes, int n_in,
                              void* d_out, int out_size, void* d_ws, size_t ws_size,
                              hipStream_t stream) {
    const float* X = (const float*)d_in[0];
    const float* W = (const float*)d_in[1];
    const int* edges = (const int*)d_in[2];
    const int E = in_sizes[2] / 2;          // 1,600,000
    const int N = in_sizes[0] / N_FEAT;     // 100,000
    const int NB = (N + 511) >> 9;          // buckets of 512 nodes (196)

    char* ws = (char*)d_ws;
    const size_t xhat_b = (size_t)(N + 1) * N_FEAT * sizeof(bf16_t);  // +1 pad row
    const size_t n4     = (size_t)N * 4;
    auto al = [](size_t x) { return (x + 255) & ~(size_t)255; };

    // ---- Plan S layout (256-aligned; Xhat rows = exactly 4 cache lines) ----
    size_t off = 0;
    int*      flag   = (int*)(ws + off);        off = 256;
    bf16_t*   Wbf    = (bf16_t*)(ws + off);     off = al(off + 128 * 128 * 2);
    bf16_t*   Xhat   = (bf16_t*)(ws + off);     off = al(off + xhat_b);
    float*    dinv   = (float*)(ws + off);      off = al(off + n4);
    int*      startA = (int*)(ws + off);        off = al(off + n4 + 4);
    unsigned* rowbuf = (unsigned*)(ws + off);   off = al(off + (size_t)E * 4);
    int*      colbuf = (int*)(ws + off);        off = al(off + (size_t)E * 4);
    int*      ecol   = (int*)(ws + off);        off = al(off + (size_t)E * 4);
    int*      hist   = (int*)(ws + off);        off = al(off + (size_t)BINB * 2 * NB * 4);
    int*      baseTab= (int*)(ws + off);        off = al(off + (size_t)BINB * 2 * NB * 4);
    int*      totals = (int*)(ws + off);        off = al(off + (size_t)(2 * NB) * 4);
    int*      famBase= (int*)(ws + off);        off = al(off + (size_t)(2 * NB + 2) * 4);
    const size_t need_S = off;

    int* cnt_col = (int*)(ws + 16 + xhat_b);
    const size_t need_A = 16 + xhat_b + n4 * 3 + 16 + (size_t)E * 4;
    const size_t need_B = 16 + xhat_b + n4;

    if (ws_size >= need_S && NB <= NBMAX && N <= 100352 && (N & 15) == 0 && E >= BINB) {
        const int ntiles = N / 16;                       // 6250
        const int GEMMB  = (ntiles + 7) / 8;             // 782
        bin_k<<<BINB + 17, 1024, 0, stream>>>(edges, E, N, NB, hist,
                                              W, Wbf, Xhat + (size_t)N * N_FEAT);
        scan_k<<<2 * NB, BINB, 0, stream>>>(hist, NB, baseTab, totals);
        bucketbase_k<<<1, 512, 0, stream>>>(totals, NB, N, famBase, startA);
        bscatter_k<<<BINB, 1024, 0, stream>>>(edges, E, N, NB, baseTab, famBase,
                                              rowbuf, colbuf);
        coldeg_k<<<NB, 1024, 0, stream>>>(colbuf, famBase, NB, N, dinv);
        rowgemm_k<<<NB + GEMMB, 512, 0, stream>>>(rowbuf, famBase, NB, N, ntiles,
                                                  startA, ecol, X, Wbf, dinv, Xhat);
        gather5_k<<<N, 64, 0, stream>>>(ecol, startA, dinv, Xhat, N, (float*)d_out);
    } else if (ws_size >= need_A) {
        bf16_t* XhatA  = (bf16_t*)(ws + 16);
        int*   cnt_row = (int*)(ws + 16 + xhat_b + n4);
        int*   cur     = (int*)(ws + 16 + xhat_b + n4 * 2);
        int*   total   = (int*)(ws + 16 + xhat_b + n4 * 3);
        int*   ecolA   = (int*)(ws + 16 + xhat_b + n4 * 3 + 16);
        float* dinvA   = (float*)cnt_col;

        hipMemsetAsync(cnt_col, 0, n4 * 2, stream);
        hipMemsetAsync(total, 0, 16, stream);
        detect_k<<<1, 64, 0, stream>>>(edges, flag);
        gemm_xwt<<<N / 16, 64, 0, stream>>>(X, W, XhatA);
        degree_k<<<(E + 255) / 256, 256, 0, stream>>>(edges, flag, E, N, cnt_row, cnt_col);
        alloc_k<<<(N + 255) / 256, 256, 0, stream>>>(cnt_row, N, cur, total, cnt_col, dinvA);
        scatter_k<<<(E + 255) / 256, 256, 0, stream>>>(edges, flag, E, N, cur, ecolA);
        gather_k<<<N, 64, 0, stream>>>(ecolA, cur, cnt_row, dinvA, XhatA, N, (float*)d_out);
    } else if (ws_size >= need_B) {
        bf16_t* XhatB = (bf16_t*)(ws + 16);
        hipMemsetAsync(cnt_col, 0, n4, stream);
        detect_k<<<1, 64, 0, stream>>>(edges, flag);
        gemm_xwt<<<N / 16, 64, 0, stream>>>(X, W, XhatB);
        degree_col_k<<<(E + 255) / 256, 256, 0, stream>>>(edges, flag, E, N, cnt_col);
        self_k<<<N, 128, 0, stream>>>(cnt_col, XhatB, (float*)d_out);
        edge_add_k<<<E, 128, 0, stream>>>(edges, flag, E, N, cnt_col, XhatB, (float*)d_out);
    }
}